// Round 4
// baseline (815.390 us; speedup 1.0000x reference)
//
#include <hip/hip_runtime.h>
#include <hip/hip_bf16.h>

// Correlation (FlowNet): out[b, 21*ky+kx, i, j] = (1/C) sum_c in1[b,c,i,j] * in2[b,c,i+2ky-20,j+2kx-20]
// Parity split j=2u+pj -> banded Gram G[u,w]=sum_c X[c,u]Y[c,w], w=u+kx-10, via 32x32x16 bf16 MFMA.
// Round 4: dword-XOR pre-swizzle in repack (conflict-free ds_read_b32 B-frags) + 77KB LDS for 2 blocks/CU.

#define NB 8
#define NC 256
#define NH 96
#define NW 128
#define NU 64
#define ND 21
#define NK 441
#define HW (NH * NW)

typedef __attribute__((ext_vector_type(8))) short s16x8;
typedef __attribute__((ext_vector_type(16))) float f32x16;

__device__ __forceinline__ unsigned short f2bf(float f) {
    unsigned int x = __float_as_uint(f);
    x += 0x7fffu + ((x >> 16) & 1u);   // RTNE
    return (unsigned short)(x >> 16);
}

// ---------------- prepass: fp32 [b][c][r][j] -> bf16 yg rows [b][pj][r][u][128 dwords],
// with logical dword q stored at physical dword (q ^ (u&31))  [dword-granular XOR swizzle]
__global__ __launch_bounds__(256) void repack4(
    const float* __restrict__ in2, unsigned int* __restrict__ yg)
{
    int bid = blockIdx.x;
    int ct = bid & 3;                  // c-tile of 64 (dwords ct*32..ct*32+31)
    int rest = bid >> 2;
    int r = rest % NH;
    int b = rest / NH;
    int c0 = ct * 64;

    __shared__ unsigned short tbuf[128][68];   // [j][c_local], +4 pad

    int tid = threadIdx.x;
    int j = tid & 127;
    int ch = tid >> 7;
    #pragma unroll 4
    for (int p = 0; p < 32; ++p) {
        int cl = p * 2 + ch;
        tbuf[j][cl] = f2bf(in2[(((size_t)b * NC + (c0 + cl)) * NH + r) * NW + j]);
    }
    __syncthreads();
    int c2 = tid & 31;                 // dword index within this c-tile
    int jr = tid >> 5;
    #pragma unroll
    for (int jj0 = 0; jj0 < 128; jj0 += 8) {
        int jj = jj0 + jr;
        int pj = jj & 1, u = jj >> 1;
        unsigned int val = *reinterpret_cast<const unsigned int*>(&tbuf[jj][2 * c2]);
        // logical dword q = ct*32 + c2 ; physical = ct*32 + (c2 ^ (u&31))
        size_t o = ((((size_t)b * 2 + pj) * NH + r) * NU + u) * 128
                 + ct * 32 + (c2 ^ (u & 31));
        yg[o] = val;
    }
}

// ---------------- main kernel ----------------
// LDS: Y[128 rows(pj,u)][512B, dword-swizzled] | G[128][25] f32 | 512B zeros
#define GOFF 65536
#define GP 25
#define ZOFF (GOFF + 128 * GP * 4)   // 78336
#define LDSZ (ZOFF + 512)            // 78848  -> 2 blocks/CU

__global__ __launch_bounds__(512, 4) void corr4(
    const float* __restrict__ in1,
    const unsigned int* __restrict__ yg,
    float* __restrict__ out)
{
    __shared__ __align__(16) unsigned char LDS[LDSZ];

    int bid = blockIdx.x;
    int b = bid & 7;           // XCD-grouped: same yg b-slab per XCD, consecutive i
    int i = bid >> 3;
    int tid = threadIdx.x;
    int lane = tid & 63;
    int wv = tid >> 6;         // 8 waves: (pj, ut, wt)
    int pj = wv >> 2;
    int ut = (wv >> 1) & 1;
    int wt = wv & 1;
    int l31 = lane & 31;
    int hp = lane >> 5;

    if (tid < 32) {
        *reinterpret_cast<uint4*>(&LDS[ZOFF + tid * 16]) = uint4{0u, 0u, 0u, 0u};
    }

    int ky0 = 21 - i; ky0 = (ky0 > 0) ? (ky0 >> 1) : 0;
    int ky1 = (115 - i) >> 1; if (ky1 > 20) ky1 = 20;
    int r0 = i + 2 * ky0 - 20;

    const unsigned int* ygb = yg + (size_t)b * 2 * NH * NU * 128;

    // issue Y(r0) loads -> regs (linear copy; swizzle already applied in repack)
    uint4 stg[8];
    #pragma unroll
    for (int m = 0; m < 8; ++m) {
        int idx = m * 512 + tid;           // 0..4095 uint4-chunks
        int rho = idx >> 5, o32 = idx & 31;
        int ps = rho >> 6, u = rho & 63;
        stg[m] = *reinterpret_cast<const uint4*>(
            ygb + (((size_t)ps * NH + r0) * NU + u) * 128 + o32 * 4);
    }

    // ---- A fragments: register-resident, direct from fp32 in1 ----
    int u_a = ut * 32 + l31;
    int j_a = 2 * u_a + pj;
    const float* arow = in1 + (((size_t)b * NC) * NH + i) * NW + j_a;
    s16x8 afr[16];
    #pragma unroll
    for (int ks = 0; ks < 16; ++ks) {
        int c0 = ks * 16 + hp * 8;
        s16x8 a;
        #pragma unroll
        for (int s = 0; s < 8; ++s) a[s] = (short)f2bf(arow[(size_t)(c0 + s) * HW]);
        afr[ks] = a;
    }

    // write Y(r0) to LDS (linear)
    #pragma unroll
    for (int m = 0; m < 8; ++m) {
        int idx = m * 512 + tid;
        *reinterpret_cast<uint4*>(&LDS[idx * 16]) = stg[m];
    }

    // zero-fill invalid ky
    int jx = tid & 127;
    int kq = tid >> 7;
    for (int ky = 0; ky < ky0; ++ky) {
        size_t ob = (((size_t)b * NK + 21 * ky) * NH + i) * NW + jx;
        for (int kx = kq; kx < ND; kx += 4) out[ob + (size_t)kx * HW] = 0.0f;
    }
    for (int ky = ky1 + 1; ky <= 20; ++ky) {
        size_t ob = (((size_t)b * NK + 21 * ky) * NH + i) * NW + jx;
        for (int kx = kq; kx < ND; kx += 4) out[ob + (size_t)kx * HW] = 0.0f;
    }

    // B row addressing (ky-invariant); invalid lanes read the 512B zero block
    int w = ut * 32 - 10 + wt * 32 + l31;
    bool bval = (w >= 0) && (w < NU);
    int rowz = bval ? ((pj * 64 + w) * 512) : ZOFF;
    int wxz = bval ? (w & 31) : 0;

    // extract addressing (ky-invariant)
    int ue = jx >> 1, pjx = jx & 1;
    const int gebase = GOFF + ((pjx * 64 + ue) * GP) * 4;

    int urow0 = pj * 64 + ut * 32;

    for (int ky = ky0; ky <= ky1; ++ky) {
        __syncthreads();               // B1: Y(ky) visible; G(ky-1) reads done

        if (ky < ky1) {                // issue Y(ky+1) loads (latency hides under MFMA)
            int r2 = i + 2 * ky - 18;
            #pragma unroll
            for (int m = 0; m < 8; ++m) {
                int idx = m * 512 + tid;
                int rho = idx >> 5, o32 = idx & 31;
                int ps = rho >> 6, u = rho & 63;
                stg[m] = *reinterpret_cast<const uint4*>(
                    ygb + (((size_t)ps * NH + r2) * NU + u) * 128 + o32 * 4);
            }
        }

        f32x16 acc;
        #pragma unroll
        for (int z = 0; z < 16; ++z) acc[z] = 0.0f;
        #pragma unroll
        for (int k8 = 0; k8 < 16; ++k8) {
            int q0 = k8 * 8 + hp * 4;      // logical dword base of this fragment
            union { unsigned int u4[4]; s16x8 v; } bf;
            #pragma unroll
            for (int d = 0; d < 4; ++d) {
                bf.u4[d] = *reinterpret_cast<const unsigned int*>(
                    &LDS[rowz + (((q0 + d) ^ wxz) << 2)]);
            }
            acc = __builtin_amdgcn_mfma_f32_32x32x16_bf16(afr[k8], bf.v, acc, 0, 0, 0);
        }

        // spill only the live band: kx = wt*32 + l31 - ur in [0,20]
        #pragma unroll
        for (int r16 = 0; r16 < 16; ++r16) {
            int ur = (r16 & 3) + 8 * (r16 >> 2) + 4 * hp;
            int kx = wt * 32 + l31 - ur;
            if (kx >= 0 && kx <= 20) {
                *reinterpret_cast<float*>(
                    &LDS[GOFF + ((urow0 + ur) * GP + kx) * 4]) = acc[r16];
            }
        }
        __syncthreads();               // B2: Y(ky) reads done; G visible

        if (ky < ky1) {                // write Y(ky+1) from staged regs (linear)
            #pragma unroll
            for (int m = 0; m < 8; ++m) {
                int idx = m * 512 + tid;
                *reinterpret_cast<uint4*>(&LDS[idx * 16]) = stg[m];
            }
        }

        // band extraction + coalesced store
        size_t ob = (((size_t)b * NK + 21 * ky) * NH + i) * NW + jx;
        for (int kx = kq; kx < ND; kx += 4) {
            out[ob + (size_t)kx * HW] =
                *reinterpret_cast<const float*>(&LDS[gebase + kx * 4]) * 0.00390625f;
        }
    }
}

// ---------------- fallback (ws too small): 1 thread per output ----------------
__global__ __launch_bounds__(256) void corr_naive(
    const float* __restrict__ in1, const float* __restrict__ in2, float* __restrict__ out)
{
    size_t o = (size_t)blockIdx.x * 256 + threadIdx.x;
    if (o >= (size_t)NB * NK * NH * NW) return;
    int j = o & 127;
    int i = (int)((o >> 7) % NH);
    size_t rest = o / ((size_t)NH * NW);
    int k = (int)(rest % NK);
    int b = (int)(rest / NK);
    int ky = k / ND, kx = k % ND;
    int r = i + 2 * ky - 20, jc = j + 2 * kx - 20;
    float s = 0.f;
    if (r >= 0 && r < NH && jc >= 0 && jc < NW) {
        const float* p1 = in1 + (((size_t)b * NC) * NH + i) * NW + j;
        const float* p2 = in2 + (((size_t)b * NC) * NH + r) * NW + jc;
        for (int c = 0; c < NC; ++c) { s += p1[0] * p2[0]; p1 += NH * NW; p2 += NH * NW; }
    }
    out[o] = s * (1.0f / 256.0f);
}

extern "C" void kernel_launch(void* const* d_in, const int* in_sizes, int n_in,
                              void* d_out, int out_size, void* d_ws, size_t ws_size,
                              hipStream_t stream) {
    const float* in1 = (const float*)d_in[0];
    const float* in2 = (const float*)d_in[1];
    float* out = (float*)d_out;

    const size_t need = (size_t)NB * 2 * NH * NU * 128 * sizeof(unsigned int);  // ~50.3 MB

    if (ws_size < need) {
        size_t total = (size_t)NB * NK * NH * NW;
        corr_naive<<<(int)((total + 255) / 256), 256, 0, stream>>>(in1, in2, out);
        return;
    }

    unsigned int* yg = (unsigned int*)d_ws;

    repack4<<<NB * NH * 4, 256, 0, stream>>>(in2, yg);
    corr4<<<NB * NH, 512, 0, stream>>>(in1, yg, out);
}

// Round 6
// 338.564 us; speedup vs baseline: 2.4084x; 2.4084x over previous
//
#include <hip/hip_runtime.h>
#include <hip/hip_bf16.h>

// Correlation (FlowNet): out[b, 21*ky+kx, i, j] = (1/C) sum_c in1[b,c,i,j] * in2[b,c,i+2ky-20,j+2kx-20]
// Parity split j=2u+pj -> banded Gram G[u,w]=sum_c X[c,u]Y[c,w], w=u+kx-10, via 32x32x16 bf16 MFMA.
// Round 6: = round 5 + explicit per-wave `s_waitcnt vmcnt(0)` fence before the consuming barrier.
// Theory: __syncthreads does NOT drain vmcnt for global_load_lds on this toolchain; each wave must
// fence its own LDS-DMA before the barrier. Single-change round to isolate that hypothesis.

#define NB 8
#define NC 256
#define NH 96
#define NW 128
#define NU 64
#define ND 21
#define NK 441
#define HW (NH * NW)

typedef __attribute__((ext_vector_type(8))) short s16x8;
typedef __attribute__((ext_vector_type(16))) float f32x16;

#define VMFENCE asm volatile("s_waitcnt vmcnt(0)" ::: "memory")

__device__ __forceinline__ unsigned short f2bf(float f) {
    unsigned int x = __float_as_uint(f);
    x += 0x7fffu + ((x >> 16) & 1u);   // RTNE
    return (unsigned short)(x >> 16);
}

__device__ __forceinline__ void gll16(const void* g, void* l) {
    __builtin_amdgcn_global_load_lds(
        (const __attribute__((address_space(1))) unsigned int*)g,
        (__attribute__((address_space(3))) unsigned int*)l, 16, 0, 0);
}

// ---------------- prepass: fp32 [b][c][r][j] -> bf16 yg rows [b][pj][r][u][128 dwords],
// logical dword q stored at physical dword q ^ ((u&15)<<1)  [pair-preserving XOR swizzle]
__global__ __launch_bounds__(256) void repack5(
    const float* __restrict__ in2, unsigned int* __restrict__ yg)
{
    int bid = blockIdx.x;
    int ct = bid & 3;                  // c-tile of 64 channels (dwords ct*32..ct*32+31)
    int rest = bid >> 2;
    int r = rest % NH;
    int b = rest / NH;
    int c0 = ct * 64;

    __shared__ unsigned short tbuf[128][68];   // [j][c_local], +4 pad

    int tid = threadIdx.x;
    int j = tid & 127;
    int ch = tid >> 7;
    #pragma unroll 4
    for (int p = 0; p < 32; ++p) {
        int cl = p * 2 + ch;
        tbuf[j][cl] = f2bf(in2[(((size_t)b * NC + (c0 + cl)) * NH + r) * NW + j]);
    }
    __syncthreads();
    int c2 = tid & 31;                 // dword index within this c-tile
    int jr = tid >> 5;
    #pragma unroll
    for (int jj0 = 0; jj0 < 128; jj0 += 8) {
        int jj = jj0 + jr;
        int pj = jj & 1, u = jj >> 1;
        unsigned int val = *reinterpret_cast<const unsigned int*>(&tbuf[jj][2 * c2]);
        size_t o = ((((size_t)b * 2 + pj) * NH + r) * NU + u) * 128
                 + ct * 32 + (c2 ^ ((u & 15) << 1));
        yg[o] = val;
    }
}

// ---------------- main kernel ----------------
// LDS: Y[128 rows(pj,u)][512B, dword-swizzled] | G[128][25] f32 | 512B zeros
#define GOFF 65536
#define GP 25
#define ZOFF (GOFF + 128 * GP * 4)   // 78336
#define LDSZ (ZOFF + 512)            // 78848  -> 2 blocks/CU

__global__ __launch_bounds__(512, 4) void corr6(
    const float* __restrict__ in1,
    const unsigned int* __restrict__ yg,
    float* __restrict__ out)
{
    __shared__ __align__(16) unsigned char LDS[LDSZ];

    int bid = blockIdx.x;
    int b = bid & 7;           // XCD-grouped: same yg b-slab per XCD, consecutive i
    int i = bid >> 3;
    int tid = threadIdx.x;
    int lane = tid & 63;
    int wv = tid >> 6;         // 8 waves: (pj, ut, wt)
    int pj = wv >> 2;
    int ut = (wv >> 1) & 1;
    int wt = wv & 1;
    int l31 = lane & 31;
    int hp = lane >> 5;

    if (tid < 32) {
        *reinterpret_cast<uint4*>(&LDS[ZOFF + tid * 16]) = uint4{0u, 0u, 0u, 0u};
    }

    int ky0 = 21 - i; ky0 = (ky0 > 0) ? (ky0 >> 1) : 0;
    int ky1 = (115 - i) >> 1; if (ky1 > 20) ky1 = 20;
    int r0 = i + 2 * ky0 - 20;

    const unsigned int* ygb = yg + (size_t)b * 2 * NH * NU * 128;

    // issue Y(r0) DMA: linear copy of 64KB (swizzle pre-baked in yg)
    {
        const unsigned int* src = ygb + ((size_t)r0) * (NU * 128);
        #pragma unroll
        for (int m = 0; m < 8; ++m) {
            int idx = m * 512 + tid;           // 0..4095 16B-chunks
            int ps = idx >> 11;                // pj-slab: +NH*NU*128 dwords apart
            int off = idx & 2047;
            gll16(src + (size_t)ps * (NH * NU * 128) + off * 4, &LDS[idx * 16]);
        }
    }

    // ---- A fragments: register-resident, direct from fp32 in1 ----
    int u_a = ut * 32 + l31;
    int j_a = 2 * u_a + pj;
    const float* arow = in1 + (((size_t)b * NC) * NH + i) * NW + j_a;
    s16x8 afr[16];
    #pragma unroll
    for (int ks = 0; ks < 16; ++ks) {
        int c0 = ks * 16 + hp * 8;
        s16x8 a;
        #pragma unroll
        for (int s = 0; s < 8; ++s) a[s] = (short)f2bf(arow[(size_t)(c0 + s) * HW]);
        afr[ks] = a;
    }

    // zero-fill invalid ky
    int jx = tid & 127;
    int kq = tid >> 7;
    for (int ky = 0; ky < ky0; ++ky) {
        size_t ob = (((size_t)b * NK + 21 * ky) * NH + i) * NW + jx;
        for (int kx = kq; kx < ND; kx += 4) out[ob + (size_t)kx * HW] = 0.0f;
    }
    for (int ky = ky1 + 1; ky <= 20; ++ky) {
        size_t ob = (((size_t)b * NK + 21 * ky) * NH + i) * NW + jx;
        for (int kx = kq; kx < ND; kx += 4) out[ob + (size_t)kx * HW] = 0.0f;
    }

    // B row addressing (ky-invariant); invalid lanes read the 512B zero block
    int w = ut * 32 - 10 + wt * 32 + l31;
    bool bval = (w >= 0) && (w < NU);
    int rowz = bval ? ((pj * 64 + w) * 512) : ZOFF;
    int xz = bval ? ((w & 15) << 1) : 0;

    // extract addressing (ky-invariant)
    int ue = jx >> 1, pjx = jx & 1;
    const int gebase = GOFF + ((pjx * 64 + ue) * GP) * 4;

    int urow0 = pj * 64 + ut * 32;

    for (int ky = ky0; ky <= ky1; ++ky) {
        // Fence: this wave's own LDS-DMA (and stray stores) complete BEFORE the barrier,
        // so correctness does not depend on __syncthreads draining vmcnt for LDS-DMA.
        VMFENCE;
        __syncthreads();               // B1: Y(ky) in LDS for all waves; extract(ky-1) done

        f32x16 acc;
        #pragma unroll
        for (int z = 0; z < 16; ++z) acc[z] = 0.0f;
        #pragma unroll
        for (int k8 = 0; k8 < 16; ++k8) {
            int q0 = k8 * 8 + hp * 4;      // logical dword base of this fragment
            union { unsigned int u4[4]; s16x8 v; } bf;
            *reinterpret_cast<uint2*>(&bf.u4[0]) =
                *reinterpret_cast<const uint2*>(&LDS[rowz + ((q0 ^ xz) << 2)]);
            *reinterpret_cast<uint2*>(&bf.u4[2]) =
                *reinterpret_cast<const uint2*>(&LDS[rowz + (((q0 + 2) ^ xz) << 2)]);
            acc = __builtin_amdgcn_mfma_f32_32x32x16_bf16(afr[k8], bf.v, acc, 0, 0, 0);
        }

        // spill only the live band: kx = wt*32 + l31 - ur in [0,20]
        #pragma unroll
        for (int r16 = 0; r16 < 16; ++r16) {
            int ur = (r16 & 3) + 8 * (r16 >> 2) + 4 * hp;
            int kx = wt * 32 + l31 - ur;
            if (kx >= 0 && kx <= 20) {
                *reinterpret_cast<float*>(
                    &LDS[GOFF + ((urow0 + ur) * GP + kx) * 4]) = acc[r16];
            }
        }
        __syncthreads();               // B2: Y(ky) reads + G writes done

        if (ky < ky1) {                // issue Y(ky+1) DMA; fenced before next B1
            int r2 = i + 2 * ky - 18;
            const unsigned int* src = ygb + ((size_t)r2) * (NU * 128);
            #pragma unroll
            for (int m = 0; m < 8; ++m) {
                int idx = m * 512 + tid;
                int ps = idx >> 11;
                int off = idx & 2047;
                gll16(src + (size_t)ps * (NH * NU * 128) + off * 4, &LDS[idx * 16]);
            }
        }

        // band extraction + coalesced store
        size_t ob = (((size_t)b * NK + 21 * ky) * NH + i) * NW + jx;
        for (int kx = kq; kx < ND; kx += 4) {
            out[ob + (size_t)kx * HW] =
                *reinterpret_cast<const float*>(&LDS[gebase + kx * 4]) * 0.00390625f;
        }
    }
}

// ---------------- fallback (ws too small): 1 thread per output ----------------
__global__ __launch_bounds__(256) void corr_naive(
    const float* __restrict__ in1, const float* __restrict__ in2, float* __restrict__ out)
{
    size_t o = (size_t)blockIdx.x * 256 + threadIdx.x;
    if (o >= (size_t)NB * NK * NH * NW) return;
    int j = o & 127;
    int i = (int)((o >> 7) % NH);
    size_t rest = o / ((size_t)NH * NW);
    int k = (int)(rest % NK);
    int b = (int)(rest / NK);
    int ky = k / ND, kx = k % ND;
    int r = i + 2 * ky - 20, jc = j + 2 * kx - 20;
    float s = 0.f;
    if (r >= 0 && r < NH && jc >= 0 && jc < NW) {
        const float* p1 = in1 + (((size_t)b * NC) * NH + i) * NW + j;
        const float* p2 = in2 + (((size_t)b * NC) * NH + r) * NW + jc;
        for (int c = 0; c < NC; ++c) { s += p1[0] * p2[0]; p1 += NH * NW; p2 += NH * NW; }
    }
    out[o] = s * (1.0f / 256.0f);
}

extern "C" void kernel_launch(void* const* d_in, const int* in_sizes, int n_in,
                              void* d_out, int out_size, void* d_ws, size_t ws_size,
                              hipStream_t stream) {
    const float* in1 = (const float*)d_in[0];
    const float* in2 = (const float*)d_in[1];
    float* out = (float*)d_out;

    const size_t need = (size_t)NB * 2 * NH * NU * 128 * sizeof(unsigned int);  // ~50.3 MB

    if (ws_size < need) {
        size_t total = (size_t)NB * NK * NH * NW;
        corr_naive<<<(int)((total + 255) / 256), 256, 0, stream>>>(in1, in2, out);
        return;
    }

    unsigned int* yg = (unsigned int*)d_ws;

    repack5<<<NB * NH * 4, 256, 0, stream>>>(in2, yg);
    corr6<<<NB * NH, 512, 0, stream>>>(in1, yg, out);
}

// Round 7
// 277.608 us; speedup vs baseline: 2.9372x; 1.2196x over previous
//
#include <hip/hip_runtime.h>
#include <hip/hip_bf16.h>

// Correlation (FlowNet): out[b, 21*ky+kx, i, j] = (1/C) sum_c in1[b,c,i,j] * in2[b,c,i+2ky-20,j+2kx-20]
// Parity split j=2u+pj -> banded Gram G[u,w]=sum_c X[c,u]Y[c,w], w=u+kx-10, via 32x32x16 bf16 MFMA.
// Round 7: NO Y-LDS staging. A register-resident; B fragments read global->VGPR per ky (L2-served).
// LDS holds only the G band buffer. Zero-row (r=96) in yg serves out-of-range w lanes.

#define NB 8
#define NC 256
#define NH 96
#define NW 128
#define NU 64
#define ND 21
#define NK 441
#define HW (NH * NW)
#define ROWDW 8192          // dwords per (pj,r) Y-row: 64 u x 512 B
#define NR 97               // 96 real rows + 1 zero row

typedef __attribute__((ext_vector_type(8))) short s16x8;
typedef __attribute__((ext_vector_type(16))) float f32x16;

__device__ __forceinline__ unsigned short f2bf(float f) {
    unsigned int x = __float_as_uint(f);
    x += 0x7fffu + ((x >> 16) & 1u);   // RTNE
    return (unsigned short)(x >> 16);
}

// ---------------- prepass: fp32 [b][c][r][j] -> bf16 yg[b][pj][r(97)][u][c] linear; row 96 = zeros
__global__ __launch_bounds__(256) void repack7(
    const float* __restrict__ in2, unsigned int* __restrict__ yg)
{
    int bid = blockIdx.x;
    int tid = threadIdx.x;

    if (bid >= NB * NH * 4) {          // zero-row writer blocks
        int b = bid - NB * NH * 4;
        uint4 z = {0u, 0u, 0u, 0u};
        #pragma unroll
        for (int p = 0; p < 2; ++p) {
            unsigned int* base = yg + ((size_t)(b * 2 + p) * NR + 96) * ROWDW;
            #pragma unroll
            for (int m = 0; m < 8; ++m) {
                *reinterpret_cast<uint4*>(base + (m * 256 + tid) * 4) = z;
            }
        }
        return;
    }

    int ct = bid & 3;                  // c-tile of 64 channels
    int rest = bid >> 2;
    int r = rest % NH;
    int b = rest / NH;
    int c0 = ct * 64;

    __shared__ unsigned short tbuf[128][68];   // [j][c_local], +4 pad

    int j = tid & 127;
    int ch = tid >> 7;
    #pragma unroll 4
    for (int p = 0; p < 32; ++p) {
        int cl = p * 2 + ch;
        tbuf[j][cl] = f2bf(in2[(((size_t)b * NC + (c0 + cl)) * NH + r) * NW + j]);
    }
    __syncthreads();
    int c2 = tid & 31;                 // dword index within c-tile
    int jr = tid >> 5;
    #pragma unroll
    for (int jj0 = 0; jj0 < 128; jj0 += 8) {
        int jj = jj0 + jr;
        int pj = jj & 1, u = jj >> 1;
        unsigned int val = *reinterpret_cast<const unsigned int*>(&tbuf[jj][2 * c2]);
        size_t o = ((size_t)(b * 2 + pj) * NR + r) * ROWDW + u * 128 + ct * 32 + c2;
        yg[o] = val;
    }
}

// ---------------- main kernel ----------------
// LDS: G[128][25] f32 only (12.8 KB)
#define GP 25
#define LDSZ (128 * GP * 4)

__global__ __launch_bounds__(512, 2) void corr7(
    const float* __restrict__ in1,
    const unsigned int* __restrict__ yg,
    float* __restrict__ out)
{
    __shared__ __align__(16) unsigned char LDS[LDSZ];

    int bid = blockIdx.x;
    int b = bid & 7;           // XCD-grouped: batch b pinned to XCD b
    int i = bid >> 3;
    int tid = threadIdx.x;
    int lane = tid & 63;
    int wv = tid >> 6;         // 8 waves: (pj, ut, wt)
    int pj = wv >> 2;
    int ut = (wv >> 1) & 1;
    int wt = wv & 1;
    int l31 = lane & 31;
    int hp = lane >> 5;

    int ky0 = 21 - i; ky0 = (ky0 > 0) ? (ky0 >> 1) : 0;
    int ky1 = (115 - i) >> 1; if (ky1 > 20) ky1 = 20;

    // ---- A fragments: register-resident, direct from fp32 in1 ----
    int u_a = ut * 32 + l31;
    int j_a = 2 * u_a + pj;
    const float* arow = in1 + (((size_t)b * NC) * NH + i) * NW + j_a;
    s16x8 afr[16];
    #pragma unroll
    for (int ks = 0; ks < 16; ++ks) {
        int c0 = ks * 16 + hp * 8;
        s16x8 a;
        #pragma unroll
        for (int s = 0; s < 8; ++s) a[s] = (short)f2bf(arow[(size_t)(c0 + s) * HW]);
        afr[ks] = a;
    }

    // zero-fill invalid ky
    int jx = tid & 127;
    int kq = tid >> 7;
    for (int ky = 0; ky < ky0; ++ky) {
        size_t ob = (((size_t)b * NK + 21 * ky) * NH + i) * NW + jx;
        for (int kx = kq; kx < ND; kx += 4) out[ob + (size_t)kx * HW] = 0.0f;
    }
    for (int ky = ky1 + 1; ky <= 20; ++ky) {
        size_t ob = (((size_t)b * NK + 21 * ky) * NH + i) * NW + jx;
        for (int kx = kq; kx < ND; kx += 4) out[ob + (size_t)kx * HW] = 0.0f;
    }

    // B addressing: wave-uniform pj slab; per-lane row w (ky-invariant part)
    const unsigned int* ygp = yg + (size_t)(b * 2 + pj) * NR * ROWDW;
    int w = ut * 32 - 10 + wt * 32 + l31;
    bool bval = (w >= 0) && (w < NU);
    int lane_dw = bval ? (w * 128) : 0;     // dword offset within row
    const int zrow_dw = 96 * ROWDW;

    // extract addressing (ky-invariant)
    int ue = jx >> 1, pjx = jx & 1;
    const int gebase = ((pjx * 64 + ue) * GP) * 4;

    int urow0 = pj * 64 + ut * 32;

    for (int ky = ky0; ky <= ky1; ++ky) {
        int r = i + 2 * ky - 20;
        int row_dw = bval ? (r * ROWDW) : zrow_dw;

        // load all 16 B-fragments global->VGPR (independent, L2-served)
        const s16x8* bp = reinterpret_cast<const s16x8*>(ygp + row_dw + lane_dw);
        s16x8 bfv[16];
        #pragma unroll
        for (int k8 = 0; k8 < 16; ++k8) bfv[k8] = bp[k8 * 2 + hp];

        f32x16 acc;
        #pragma unroll
        for (int z = 0; z < 16; ++z) acc[z] = 0.0f;
        #pragma unroll
        for (int k8 = 0; k8 < 16; ++k8) {
            acc = __builtin_amdgcn_mfma_f32_32x32x16_bf16(afr[k8], bfv[k8], acc, 0, 0, 0);
        }

        // spill live band: kx = w - u + 10 = wt*32 + l31 - ur in [0,20]
        #pragma unroll
        for (int r16 = 0; r16 < 16; ++r16) {
            int ur = (r16 & 3) + 8 * (r16 >> 2) + 4 * hp;
            int kx = wt * 32 + l31 - ur;
            if (kx >= 0 && kx <= 20) {
                *reinterpret_cast<float*>(
                    &LDS[((urow0 + ur) * GP + kx) * 4]) = acc[r16];
            }
        }
        __syncthreads();               // B1: G(ky) ready

        // band extraction + coalesced store
        size_t ob = (((size_t)b * NK + 21 * ky) * NH + i) * NW + jx;
        for (int kx = kq; kx < ND; kx += 4) {
            out[ob + (size_t)kx * HW] =
                *reinterpret_cast<const float*>(&LDS[gebase + kx * 4]) * 0.00390625f;
        }
        __syncthreads();               // B2: extract done, G free
    }
}

// ---------------- fallback (ws too small): 1 thread per output ----------------
__global__ __launch_bounds__(256) void corr_naive(
    const float* __restrict__ in1, const float* __restrict__ in2, float* __restrict__ out)
{
    size_t o = (size_t)blockIdx.x * 256 + threadIdx.x;
    if (o >= (size_t)NB * NK * NH * NW) return;
    int j = o & 127;
    int i = (int)((o >> 7) % NH);
    size_t rest = o / ((size_t)NH * NW);
    int k = (int)(rest % NK);
    int b = (int)(rest / NK);
    int ky = k / ND, kx = k % ND;
    int r = i + 2 * ky - 20, jc = j + 2 * kx - 20;
    float s = 0.f;
    if (r >= 0 && r < NH && jc >= 0 && jc < NW) {
        const float* p1 = in1 + (((size_t)b * NC) * NH + i) * NW + j;
        const float* p2 = in2 + (((size_t)b * NC) * NH + r) * NW + jc;
        for (int c = 0; c < NC; ++c) { s += p1[0] * p2[0]; p1 += NH * NW; p2 += NH * NW; }
    }
    out[o] = s * (1.0f / 256.0f);
}

extern "C" void kernel_launch(void* const* d_in, const int* in_sizes, int n_in,
                              void* d_out, int out_size, void* d_ws, size_t ws_size,
                              hipStream_t stream) {
    const float* in1 = (const float*)d_in[0];
    const float* in2 = (const float*)d_in[1];
    float* out = (float*)d_out;

    const size_t need = (size_t)NB * 2 * NR * ROWDW * sizeof(unsigned int);  // ~48.5 MB

    if (ws_size < need) {
        size_t total = (size_t)NB * NK * NH * NW;
        corr_naive<<<(int)((total + 255) / 256), 256, 0, stream>>>(in1, in2, out);
        return;
    }

    unsigned int* yg = (unsigned int*)d_ws;

    repack7<<<NB * NH * 4 + NB, 256, 0, stream>>>(in2, yg);
    corr7<<<NB * NH, 512, 0, stream>>>(in1, yg, out);
}

// Round 8
// 236.160 us; speedup vs baseline: 3.4527x; 1.1755x over previous
//
#include <hip/hip_runtime.h>
#include <hip/hip_bf16.h>

// Correlation (FlowNet): out[b, 21*ky+kx, i, j] = (1/C) sum_c in1[b,c,i,j] * in2[b,c,i+2ky-20,j+2kx-20]
// Parity split j=2u+pj -> banded Gram G[u,w]=sum_c X[c,u]Y[c,w], w=u+kx-10, via 32x32x16 bf16 MFMA.
// Round 8: chunk-major yg [b][pj][r][chunk32][slot96][16B] (slot=w+10, pads zeroed) -> B loads are
// lane-contiguous 512B segments; B prefetch for ky+1 issued under the G spill/extract phase.

#define NB 8
#define NC 256
#define NH 96
#define NW 128
#define NU 64
#define ND 21
#define NK 441
#define HW (NH * NW)
#define NSLOT 96
#define CHDW (NSLOT * 4)          // dwords per chunk: 96 slots x 16B = 384 dw
#define ROWDW (32 * CHDW)         // dwords per (pj,r) row: 12288
#define PJDW ((size_t)NH * ROWDW) // dwords per pj slab

typedef __attribute__((ext_vector_type(8))) short s16x8;
typedef __attribute__((ext_vector_type(16))) float f32x16;

__device__ __forceinline__ unsigned short f2bf(float f) {
    unsigned int x = __float_as_uint(f);
    x += 0x7fffu + ((x >> 16) & 1u);   // RTNE
    return (unsigned short)(x >> 16);
}

// ---------------- prepass: fp32 [b][c][r][j] -> bf16 chunk-major yg; pad slots zeroed
__global__ __launch_bounds__(256) void repack8(
    const float* __restrict__ in2, unsigned int* __restrict__ yg)
{
    int bid = blockIdx.x;
    int ct = bid & 3;                  // covers chunks ct*8 .. ct*8+7 (channels ct*64..+63)
    int rest = bid >> 2;
    int r = rest % NH;
    int b = rest / NH;
    int c0 = ct * 64;

    __shared__ unsigned short tbuf[128][68];   // [j][c_local], +4 pad

    int tid = threadIdx.x;
    int j = tid & 127;
    int ch = tid >> 7;
    #pragma unroll 4
    for (int p = 0; p < 32; ++p) {
        int cl = p * 2 + ch;
        tbuf[j][cl] = f2bf(in2[(((size_t)b * NC + (c0 + cl)) * NH + r) * NW + j]);
    }
    __syncthreads();

    // real data: item = [pj(1)][cl8(3)][u(6)][d(2)]  (d,u from tid -> contiguous global writes)
    #pragma unroll
    for (int it = 0; it < 16; ++it) {
        int item = it * 256 + tid;
        int d = item & 3;
        int u = (item >> 2) & 63;
        int cl8 = (item >> 8) & 7;
        int pj = item >> 11;
        unsigned int val = *reinterpret_cast<const unsigned int*>(&tbuf[2 * u + pj][cl8 * 8 + d * 2]);
        size_t o = ((size_t)(b * 2 + pj) * NH + r) * ROWDW
                 + (size_t)(ct * 8 + cl8) * CHDW + (u + 10) * 4 + d;
        yg[o] = val;
    }
    // zero pads: slots 0..9 (w=-10..-1) and 74..95 (w=64..85) for this block's 8 chunks
    #pragma unroll
    for (int it = 0; it < 8; ++it) {
        int item = it * 256 + tid;
        int d = item & 3;
        int zs = (item >> 2) & 31;
        int cl8 = (item >> 7) & 7;
        int pj = item >> 10;
        int slot = (zs < 10) ? zs : (zs + 64);
        size_t o = ((size_t)(b * 2 + pj) * NH + r) * ROWDW
                 + (size_t)(ct * 8 + cl8) * CHDW + slot * 4 + d;
        yg[o] = 0u;
    }
}

// ---------------- main kernel ----------------
// LDS: G[128][25] f32 only (12.8 KB)
#define GP 25
#define LDSZ (128 * GP * 4)

__global__ __launch_bounds__(512, 2) void corr8(
    const float* __restrict__ in1,
    const unsigned int* __restrict__ yg,
    float* __restrict__ out)
{
    __shared__ __align__(16) unsigned char LDS[LDSZ];

    int bid = blockIdx.x;
    int b = bid & 7;           // XCD-grouped: batch b pinned to XCD b
    int i = bid >> 3;
    int tid = threadIdx.x;
    int lane = tid & 63;
    int wv = tid >> 6;         // 8 waves: (pj, ut, wt)
    int pj = wv >> 2;
    int ut = (wv >> 1) & 1;
    int wt = wv & 1;
    int l31 = lane & 31;
    int hp = lane >> 5;

    int ky0 = 21 - i; ky0 = (ky0 > 0) ? (ky0 >> 1) : 0;
    int ky1 = (115 - i) >> 1; if (ky1 > 20) ky1 = 20;

    // B lane base: slot = w+10 = ut*32+wt*32+l31; hp selects odd/even chunk
    const unsigned int* lanebase = yg + (size_t)(b * 2 + pj) * PJDW
                                 + (size_t)hp * CHDW
                                 + (ut * 32 + wt * 32 + l31) * 4;

    s16x8 bfv[16];
    {   // prologue: load Y(ky0)
        const unsigned int* p = lanebase + (size_t)(i + 2 * ky0 - 20) * ROWDW;
        #pragma unroll
        for (int k8 = 0; k8 < 16; ++k8)
            bfv[k8] = *reinterpret_cast<const s16x8*>(p + (size_t)k8 * (2 * CHDW));
    }

    // ---- A fragments: register-resident, direct from fp32 in1 ----
    int u_a = ut * 32 + l31;
    int j_a = 2 * u_a + pj;
    const float* arow = in1 + (((size_t)b * NC) * NH + i) * NW + j_a;
    s16x8 afr[16];
    #pragma unroll
    for (int ks = 0; ks < 16; ++ks) {
        int c0 = ks * 16 + hp * 8;
        s16x8 a;
        #pragma unroll
        for (int s = 0; s < 8; ++s) a[s] = (short)f2bf(arow[(size_t)(c0 + s) * HW]);
        afr[ks] = a;
    }

    // zero-fill invalid ky
    int jx = tid & 127;
    int kq = tid >> 7;
    for (int ky = 0; ky < ky0; ++ky) {
        size_t ob = (((size_t)b * NK + 21 * ky) * NH + i) * NW + jx;
        for (int kx = kq; kx < ND; kx += 4) out[ob + (size_t)kx * HW] = 0.0f;
    }
    for (int ky = ky1 + 1; ky <= 20; ++ky) {
        size_t ob = (((size_t)b * NK + 21 * ky) * NH + i) * NW + jx;
        for (int kx = kq; kx < ND; kx += 4) out[ob + (size_t)kx * HW] = 0.0f;
    }

    // extract addressing (ky-invariant)
    int ue = jx >> 1, pjx = jx & 1;
    const int gebase = ((pjx * 64 + ue) * GP) * 4;

    int urow0 = pj * 64 + ut * 32;

    for (int ky = ky0; ky <= ky1; ++ky) {
        f32x16 acc;
        #pragma unroll
        for (int z = 0; z < 16; ++z) acc[z] = 0.0f;
        #pragma unroll
        for (int k8 = 0; k8 < 16; ++k8) {
            acc = __builtin_amdgcn_mfma_f32_32x32x16_bf16(afr[k8], bfv[k8], acc, 0, 0, 0);
        }

        if (ky < ky1) {       // prefetch Y(ky+1); flies under spill/extract/barriers
            const unsigned int* p = lanebase + (size_t)(i + 2 * ky - 18) * ROWDW;
            #pragma unroll
            for (int k8 = 0; k8 < 16; ++k8)
                bfv[k8] = *reinterpret_cast<const s16x8*>(p + (size_t)k8 * (2 * CHDW));
        }

        // spill live band: kx = w - u + 10 = wt*32 + l31 - ur in [0,20]
        #pragma unroll
        for (int r16 = 0; r16 < 16; ++r16) {
            int ur = (r16 & 3) + 8 * (r16 >> 2) + 4 * hp;
            int kx = wt * 32 + l31 - ur;
            if (kx >= 0 && kx <= 20) {
                *reinterpret_cast<float*>(
                    &LDS[((urow0 + ur) * GP + kx) * 4]) = acc[r16];
            }
        }
        __syncthreads();               // B1: G(ky) ready

        // band extraction + coalesced store
        size_t ob = (((size_t)b * NK + 21 * ky) * NH + i) * NW + jx;
        for (int kx = kq; kx < ND; kx += 4) {
            out[ob + (size_t)kx * HW] =
                *reinterpret_cast<const float*>(&LDS[gebase + kx * 4]) * 0.00390625f;
        }
        __syncthreads();               // B2: extract done, G free
    }
}

// ---------------- fallback (ws too small): 1 thread per output ----------------
__global__ __launch_bounds__(256) void corr_naive(
    const float* __restrict__ in1, const float* __restrict__ in2, float* __restrict__ out)
{
    size_t o = (size_t)blockIdx.x * 256 + threadIdx.x;
    if (o >= (size_t)NB * NK * NH * NW) return;
    int j = o & 127;
    int i = (int)((o >> 7) % NH);
    size_t rest = o / ((size_t)NH * NW);
    int k = (int)(rest % NK);
    int b = (int)(rest / NK);
    int ky = k / ND, kx = k % ND;
    int r = i + 2 * ky - 20, jc = j + 2 * kx - 20;
    float s = 0.f;
    if (r >= 0 && r < NH && jc >= 0 && jc < NW) {
        const float* p1 = in1 + (((size_t)b * NC) * NH + i) * NW + j;
        const float* p2 = in2 + (((size_t)b * NC) * NH + r) * NW + jc;
        for (int c = 0; c < NC; ++c) { s += p1[0] * p2[0]; p1 += NH * NW; p2 += NH * NW; }
    }
    out[o] = s * (1.0f / 256.0f);
}

extern "C" void kernel_launch(void* const* d_in, const int* in_sizes, int n_in,
                              void* d_out, int out_size, void* d_ws, size_t ws_size,
                              hipStream_t stream) {
    const float* in1 = (const float*)d_in[0];
    const float* in2 = (const float*)d_in[1];
    float* out = (float*)d_out;

    const size_t need = (size_t)NB * 2 * NH * ROWDW * sizeof(unsigned int);  // ~75.5 MB

    if (ws_size < need) {
        size_t total = (size_t)NB * NK * NH * NW;
        corr_naive<<<(int)((total + 255) / 256), 256, 0, stream>>>(in1, in2, out);
        return;
    }

    unsigned int* yg = (unsigned int*)d_ws;

    repack8<<<NB * NH * 4, 256, 0, stream>>>(in2, yg);
    corr8<<<NB * NH, 512, 0, stream>>>(in1, yg, out);
}